// Round 3
// baseline (120.349 us; speedup 1.0000x reference)
//
#include <hip/hip_runtime.h>
#include <math.h>

#define BB 128
#define PP 1024
#define LL 128
#define NROWS (BB * PP)   // 131072
#define EPS_VAR 1e-5f
#define CHUNKS 8
#define CP (PP / CHUNKS)  // 128 patches per chunk

typedef float vfloat4 __attribute__((ext_vector_type(4)));  // clang-native, OK for nontemporal builtins

__device__ __forceinline__ bool is_nan_bits(float f) {
    return (__float_as_uint(f) & 0x7fffffffu) > 0x7f800000u;
}

// ---------------------------------------------------------------------------
// Kernel 1: per-row (b,p) NaN-aware sum, sum-of-squares, nan count.
// Each 32-lane half-wave handles 2 consecutive rows (2 float4 loads/thread
// in flight for ILP). Butterfly reduce within the 32-lane half.
// ---------------------------------------------------------------------------
__global__ __launch_bounds__(256) void k_rowstats(const float* __restrict__ x,
                                                  float4* __restrict__ stats) {
    const int sl = threadIdx.x & 31;                       // sub-lane in half-wave
    const int hw = (blockIdx.x * 256 + threadIdx.x) >> 5;  // global half-wave id
    const int row0 = hw * 2;
    const int row1 = row0 + 1;

    const float4 v0 = ((const float4*)(x + (size_t)row0 * LL))[sl];
    const float4 v1 = ((const float4*)(x + (size_t)row1 * LL))[sl];

    float s1a = 0.f, s2a = 0.f, ca = 0.f;
    float s1b = 0.f, s2b = 0.f, cb = 0.f;
    {
        const float fa[4] = {v0.x, v0.y, v0.z, v0.w};
        const float fb[4] = {v1.x, v1.y, v1.z, v1.w};
#pragma unroll
        for (int j = 0; j < 4; ++j) {
            const bool na = is_nan_bits(fa[j]);
            const float va = na ? 0.f : fa[j];
            s1a += va; s2a += va * va; ca += na ? 1.f : 0.f;
            const bool nb = is_nan_bits(fb[j]);
            const float vb = nb ? 0.f : fb[j];
            s1b += vb; s2b += vb * vb; cb += nb ? 1.f : 0.f;
        }
    }
#pragma unroll
    for (int off = 16; off >= 1; off >>= 1) {
        s1a += __shfl_xor(s1a, off);
        s2a += __shfl_xor(s2a, off);
        ca  += __shfl_xor(ca,  off);
        s1b += __shfl_xor(s1b, off);
        s2b += __shfl_xor(s2b, off);
        cb  += __shfl_xor(cb,  off);
    }
    if (sl == 0) {
        stats[row0] = make_float4(s1a, s2a, ca, 0.f);
        stats[row1] = make_float4(s1b, s2b, cb, 0.f);
    }
}

// ---------------------------------------------------------------------------
// Kernel 2 (fused scan + normalize): grid = BB * CHUNKS blocks of 256.
// Each block redundantly re-scans ALL 1024 row-stats of its b (16 KiB, hot in
// L2/L3; ~20 shuffle ops), caches per-patch (mean, 1/std) in LDS, then
// normalizes its 128-patch chunk with float4 I/O + nontemporal stores.
// No cross-block dependency -> no cooperative launch needed; removes the
// serial k_scan dispatch and one device-wide barrier from the critical path.
// ---------------------------------------------------------------------------
__global__ __launch_bounds__(256) void k_scan_norm(const float* __restrict__ x,
                                                   const float4* __restrict__ stats,
                                                   float* __restrict__ out) {
    __shared__ float2 ms_s[PP];          // 8 KiB: (mean, istd) for all patches of b
    __shared__ float w1[4], w2[4], wc[4];

    const int t     = threadIdx.x;
    const int lane  = t & 63;
    const int wav   = t >> 6;
    const int b     = blockIdx.x >> 3;   // / CHUNKS
    const int chunk = blockIdx.x & (CHUNKS - 1);

    // ---- phase 1: block-wide inclusive scan of (s1, s2, nancnt) over P ----
    const size_t sbase = (size_t)b * PP + t * 4;
    float4 r[4];
#pragma unroll
    for (int j = 0; j < 4; ++j) r[j] = stats[sbase + j];

    float i1[4], i2[4], ic[4];
    i1[0] = r[0].x; i2[0] = r[0].y; ic[0] = r[0].z;
#pragma unroll
    for (int j = 1; j < 4; ++j) {
        i1[j] = i1[j - 1] + r[j].x;
        i2[j] = i2[j - 1] + r[j].y;
        ic[j] = ic[j - 1] + r[j].z;
    }
    const float t1 = i1[3], t2 = i2[3], tc = ic[3];

    float c1 = t1, c2 = t2, cc = tc;
#pragma unroll
    for (int off = 1; off < 64; off <<= 1) {
        const float a   = __shfl_up(c1, off);
        const float bb2 = __shfl_up(c2, off);
        const float cc2 = __shfl_up(cc, off);
        if (lane >= off) { c1 += a; c2 += bb2; cc += cc2; }
    }
    const float e1 = c1 - t1, e2 = c2 - t2, ec = cc - tc;

    if (lane == 63) { w1[wav] = c1; w2[wav] = c2; wc[wav] = cc; }
    __syncthreads();

    float p1 = 0.f, p2 = 0.f, pc = 0.f;
#pragma unroll
    for (int k = 0; k < 3; ++k) {
        if (wav > k) { p1 += w1[k]; p2 += w2[k]; pc += wc[k]; }
    }

    const float b1 = p1 + e1, b2 = p2 + e2, bc = pc + ec;
#pragma unroll
    for (int j = 0; j < 4; ++j) {
        const int p = t * 4 + j;
        const float cum1 = b1 + i1[j];
        const float cum2 = b2 + i2[j];
        const float cumc = bc + ic[j];
        const float cnt  = (float)(p + 1) * (float)LL - cumc;
        const float mean = cum1 / cnt;
        const float var  = cum2 / cnt - mean * mean;
        const float istd = 1.0f / sqrtf(var + EPS_VAR);
        ms_s[p] = make_float2(mean, istd);
    }
    __syncthreads();

    // ---- phase 2: normalize this block's 128-patch chunk ----
    const int sl  = t & 31;              // sub-lane in half-wave
    const int hwl = t >> 5;              // local half-wave id 0..7
    const size_t bbase = (size_t)b * PP * LL;
    const int p0 = chunk * CP;

    for (int i = 0; i < CP; i += 16) {
        const int pa = p0 + i + hwl;
        const int pb = pa + 8;
        const size_t basea = bbase + (size_t)pa * LL;
        const size_t baseb = bbase + (size_t)pb * LL;

        const float4 v0 = ((const float4*)(x + basea))[sl];
        const float4 v1 = ((const float4*)(x + baseb))[sl];
        const float2 m0 = ms_s[pa];
        const float2 m1 = ms_s[pb];

        float4 y0, y1;
        y0.x = (v0.x - m0.x) * m0.y; y0.y = (v0.y - m0.x) * m0.y;
        y0.z = (v0.z - m0.x) * m0.y; y0.w = (v0.w - m0.x) * m0.y;
        y1.x = (v1.x - m1.x) * m1.y; y1.y = (v1.y - m1.x) * m1.y;
        y1.z = (v1.z - m1.x) * m1.y; y1.w = (v1.w - m1.x) * m1.y;

        const bool anynan = is_nan_bits(v0.x) | is_nan_bits(v0.y) | is_nan_bits(v0.z) |
                            is_nan_bits(v0.w) | is_nan_bits(v1.x) | is_nan_bits(v1.y) |
                            is_nan_bits(v1.z) | is_nan_bits(v1.w);

        if (__ballot(anynan) == 0ull) {
            // fast path: vectorized nontemporal stores (out is write-once)
            vfloat4 w0 = {y0.x, y0.y, y0.z, y0.w};
            vfloat4 wv1 = {y1.x, y1.y, y1.z, y1.w};
            __builtin_nontemporal_store(w0,  &((vfloat4*)(out + basea))[sl]);
            __builtin_nontemporal_store(wv1, &((vfloat4*)(out + baseb))[sl]);
        } else {
            // slow path (never taken on NaN-free bench input)
            const size_t bases[2] = {basea, baseb};
            const float2 mm[2] = {m0, m1};
            const float4 vv[2] = {v0, v1};
            const float4 yy[2] = {y0, y1};
#pragma unroll
            for (int rr = 0; rr < 2; ++rr) {
                const float yf[4] = {yy[rr].x, yy[rr].y, yy[rr].z, yy[rr].w};
                const float vf[4] = {vv[rr].x, vv[rr].y, vv[rr].z, vv[rr].w};
                for (int j = 0; j < 4; ++j) {
                    const int l = sl * 4 + j;
                    if (!is_nan_bits(vf[j])) {
                        out[bases[rr] + l] = yf[j];
                    } else {
                        float res = 0.0f;  // x_temp[0]==0 when no prior valid exists
                        for (int k = l - 1; k >= 0; --k) {
                            const float xv = x[bases[rr] + k];
                            if (!is_nan_bits(xv)) {
                                res = (xv - mm[rr].x) * mm[rr].y;
                                break;
                            }
                        }
                        out[bases[rr] + l] = res;
                    }
                }
            }
        }
    }
}

extern "C" void kernel_launch(void* const* d_in, const int* in_sizes, int n_in,
                              void* d_out, int out_size, void* d_ws, size_t ws_size,
                              hipStream_t stream) {
    const float* x = (const float*)d_in[0];
    float* out = (float*)d_out;

    float4* stats = (float4*)d_ws;  // 2 MiB row stats (s1, s2, nancnt, pad)

    // 2 rows per half-wave -> 16 rows per 256-thread block
    k_rowstats<<<NROWS / 16, 256, 0, stream>>>(x, stats);
    // fused scan + normalize: 128 b x 8 chunks = 1024 blocks (4 blocks/CU)
    k_scan_norm<<<BB * CHUNKS, 256, 0, stream>>>(x, stats, out);
}